// Round 2
// baseline (447.304 us; speedup 1.0000x reference)
//
#include <hip/hip_runtime.h>

// PILayer: out = tanh((prop[idx_i] + basis + prop[idx_j]) @ W1 + b1) @ W2 + b2
// E=320000, D_IN=128, D_HID=256, D_OUT=128. fp32 in/out, fp16 MFMA internally.
// R2: TM=32 tile, unioned sA/sH LDS (16.9 KB/block) -> target 24 waves/CU.

#define N_EDGES 320000
#define DI 128
#define DH 256
#define DO 128
#define TM 32   // edges per block tile

typedef _Float16 half8v __attribute__((ext_vector_type(8)));
typedef _Float16 half4v __attribute__((ext_vector_type(4)));
typedef float floatx16 __attribute__((ext_vector_type(16)));

__device__ __forceinline__ float fast_tanh(float x) {
    // tanh(x) = 1 - 2/(exp(2x)+1); exact limits at +/-inf, no abs/copysign needed
    float e = __builtin_amdgcn_exp2f(x * 2.885390081777927f);  // exp(2x)
    return 1.0f - 2.0f * __builtin_amdgcn_rcpf(e + 1.0f);
}

// ---------------------------------------------------------------------------
// Prologue: transpose+convert W1[128][256] -> W1T fp16 [256][128],
//                             W2[256][128] -> W2T fp16 [128][256]
// ---------------------------------------------------------------------------
__global__ __launch_bounds__(256) void wconvert(
    const float* __restrict__ W1, const float* __restrict__ W2,
    _Float16* __restrict__ W1T, _Float16* __restrict__ W2T)
{
    __shared__ float sT[32][33];
    int b = blockIdx.x;
    const float* src; _Float16* dst; int R, C, r0, c0;
    if (b < 32) { src = W1; dst = W1T; R = DI;  C = DH; r0 = (b & 3) * 32;  c0 = (b >> 2) * 32; }
    else { b -= 32; src = W2; dst = W2T; R = DH; C = DO; r0 = (b & 7) * 32; c0 = (b >> 3) * 32; }

    const int tid = threadIdx.x;
    const int cc = tid & 31, rr = tid >> 5;
    #pragma unroll
    for (int p = 0; p < 4; ++p) {
        int r = rr + p * 8;
        sT[r][cc] = src[(size_t)(r0 + r) * C + c0 + cc];
    }
    __syncthreads();
    #pragma unroll
    for (int p = 0; p < 4; ++p) {
        int c = rr + p * 8;                 // dst row = src col
        dst[(size_t)(c0 + c) * R + r0 + cc] = (_Float16)sT[cc][c];
    }
}

// ---------------------------------------------------------------------------
// Main fused kernel: one block = one 32-edge tile, 4 waves (256 thr).
//   stage inter(fp16)->sA | B1 | GEMM1 (B from W1T global) | B2 |
//   tanh -> sH (aliases sA) | B3 | GEMM2 (B from W2T) -> +b2 -> store
// mfma_f32_32x32x16_f16: A lane l: m=l&31, k=(l>>5)*8+j
//                        B lane l: n=l&31, k=(l>>5)*8+j  (contig in W^T)
//                        C/D lane l reg r: col=l&31, row=(r&3)+8*(r>>2)+4*(l>>5)
// ---------------------------------------------------------------------------
#define SA_STRIDE (DI + 8)   // 136 halfs; 68 dwords -> conflict-free b128 reads
#define SH_STRIDE (DH + 8)   // 264 halfs; 132 dwords -> conflict-free b128 reads
#define SMEM_BYTES (TM * SH_STRIDE * 2)   // 16896; sA (8704) aliases front

__global__ __launch_bounds__(256, 6) void pilayer_main(
    const int* __restrict__ idx_i, const int* __restrict__ idx_j,
    const float* __restrict__ prop, const float* __restrict__ basis,
    const _Float16* __restrict__ W1T, const float* __restrict__ b1,
    const _Float16* __restrict__ W2T, const float* __restrict__ b2,
    float* __restrict__ out)
{
    __shared__ char smem[SMEM_BYTES];
    _Float16 (*sA)[SA_STRIDE] = (_Float16 (*)[SA_STRIDE])smem;
    _Float16 (*sH)[SH_STRIDE] = (_Float16 (*)[SH_STRIDE])smem;

    const int tid = threadIdx.x;
    const int e0 = blockIdx.x * TM;

    // ---- stage inter = prop[i] + basis + prop[j] as fp16 into sA ----
    {
        const int c4 = (tid & 31) * 4;     // col 0..124
        const int r0 = tid >> 5;           // 0..7
        #pragma unroll
        for (int p = 0; p < 4; ++p) {
            const int r = r0 + p * 8;      // 0..31
            const int e = e0 + r;
            const int ii = idx_i[e], jj = idx_j[e];
            const float4 a = *(const float4*)(prop  + (size_t)ii * DI + c4);
            const float4 bv = *(const float4*)(prop + (size_t)jj * DI + c4);
            const float4 c = *(const float4*)(basis + (size_t)e  * DI + c4);
            half4v hv;
            hv[0] = (_Float16)(a.x + bv.x + c.x);
            hv[1] = (_Float16)(a.y + bv.y + c.y);
            hv[2] = (_Float16)(a.z + bv.z + c.z);
            hv[3] = (_Float16)(a.w + bv.w + c.w);
            *(half4v*)(&sA[r][c4]) = hv;
        }
    }
    __syncthreads();   // B1

    const int w  = tid >> 6;       // wave 0..3
    const int l  = tid & 63;
    const int lm = l & 31;         // m / n within 32x32 tile
    const int lk = (l >> 5) * 8;   // k sub-offset
    const int rowq = 4 * (l >> 5); // row quad base for C/D layout

    // ---- GEMM1: h[32 x 256], wave w owns hid cols [w*64, w*64+64) ----
    floatx16 hacc[2] = {};         // [nt]
    {
        const _Float16* w1p = W1T + (size_t)(w * 64 + lm) * DI + lk;
        #pragma unroll 2
        for (int kt = 0; kt < 8; ++kt) {
            const int ko = kt * 16;
            half8v a0 = *(const half8v*)(&sA[lm][ko + lk]);
            half8v b0 = *(const half8v*)(w1p + ko);
            half8v b1f = *(const half8v*)(w1p + 32 * DI + ko);
            hacc[0] = __builtin_amdgcn_mfma_f32_32x32x16_f16(a0, b0,  hacc[0], 0, 0, 0);
            hacc[1] = __builtin_amdgcn_mfma_f32_32x32x16_f16(a0, b1f, hacc[1], 0, 0, 0);
        }
    }
    __syncthreads();   // B2: all GEMM1 reads of sA done before sH overwrite

    // ---- bias + tanh, write h to sH (C-layout -> memory layout) ----
    {
        const float bias0 = b1[w * 64 + lm];
        const float bias1 = b1[w * 64 + 32 + lm];
        #pragma unroll
        for (int r = 0; r < 16; ++r) {
            const int row = (r & 3) + 8 * (r >> 2) + rowq;   // 0..31
            sH[row][w * 64 + lm]      = (_Float16)fast_tanh(hacc[0][r] + bias0);
            sH[row][w * 64 + 32 + lm] = (_Float16)fast_tanh(hacc[1][r] + bias1);
        }
    }
    __syncthreads();   // B3

    // ---- GEMM2: out[32 x 128], wave w owns out cols [w*32, w*32+32) ----
    floatx16 oacc = {};
    {
        const _Float16* w2p = W2T + (size_t)(w * 32 + lm) * DH + lk;
        #pragma unroll 2
        for (int kt = 0; kt < 16; ++kt) {
            const int ko = kt * 16;
            half8v a0 = *(const half8v*)(&sH[lm][ko + lk]);
            half8v bb = *(const half8v*)(w2p + ko);
            oacc = __builtin_amdgcn_mfma_f32_32x32x16_f16(a0, bb, oacc, 0, 0, 0);
        }
    }

    // ---- epilogue: + b2, store fp32 ----
    {
        const int col = w * 32 + lm;
        const float bias = b2[col];
        #pragma unroll
        for (int r = 0; r < 16; ++r) {
            const int row = e0 + (r & 3) + 8 * (r >> 2) + rowq;
            out[(size_t)row * DO + col] = oacc[r] + bias;
        }
    }
}

extern "C" void kernel_launch(void* const* d_in, const int* in_sizes, int n_in,
                              void* d_out, int out_size, void* d_ws, size_t ws_size,
                              hipStream_t stream) {
    const int*   idx_i = (const int*)d_in[0];
    const int*   idx_j = (const int*)d_in[1];
    const float* prop  = (const float*)d_in[2];
    const float* basis = (const float*)d_in[3];
    const float* W1    = (const float*)d_in[4];
    const float* b1    = (const float*)d_in[5];
    const float* W2    = (const float*)d_in[6];
    const float* b2    = (const float*)d_in[7];
    float* out = (float*)d_out;

    _Float16* W1T = (_Float16*)d_ws;            // [256][128] = 64 KB
    _Float16* W2T = W1T + (size_t)DI * DH;      // [128][256] = 64 KB

    wconvert<<<64, 256, 0, stream>>>(W1, W2, W1T, W2T);
    pilayer_main<<<N_EDGES / TM, 256, 0, stream>>>(idx_i, idx_j, prop, basis,
                                                   W1T, b1, W2T, b2, out);
}